// Round 6
// baseline (245.085 us; speedup 1.0000x reference)
//
#include <hip/hip_runtime.h>

typedef unsigned short ushort_t;
typedef __attribute__((ext_vector_type(8))) short short8;
typedef __attribute__((ext_vector_type(4))) float floatx4;
typedef __attribute__((ext_vector_type(4))) unsigned uintx4;

#define G_   129
#define F_   96
#define O_   96
#define T_   512
#define KD   288    // K*F, kd = kk*96 + f
#define LDB  296    // Wl padded row stride (288 + 8)

// f32 -> bf16 RNE (finite inputs) — used for the weight stage
__device__ __forceinline__ unsigned f2bf(float f) {
    unsigned u = __builtin_bit_cast(unsigned, f);
    u += 0x7FFFu + ((u >> 16) & 1u);
    return u >> 16;
}
__device__ __forceinline__ unsigned pk2(float a, float b) {
    return f2bf(a) | (f2bf(b) << 16);
}
// HW packed convert (RNE, same results): 1 inst per 2 floats
__device__ __forceinline__ unsigned cvtpk(float lo, float hi) {
    unsigned r;
    asm("v_cvt_pk_bf16_f32 %0, %1, %2" : "=v"(r) : "v"(lo), "v"(hi));
    return r;
}

// Round-2 geometry (1032 blocks: 129 g x 8 m-tiles of 256, full O=96 — best
// measured write/fetch behavior), but x is NO LONGER staged through LDS:
// each lane's A-fragment (8 consecutive f32 of one x row) is loaded directly
// from global (2x dwordx4) and packed with v_cvt_pk_bf16_f32. The 3x kk
// re-read is L1-resident. x loads now issue in three bursts spread across the
// compute phase (fb0 under the weight stage+barrier, fb+1 under fb's MFMAs),
// keeping global reads in flight for the whole block instead of one upfront
// burst (r2-r5 lesson: achieved BW pinned ~2.5 TB/s by memory duty cycle).
// XCD-colocated decode (g%8) keeps each group's w and x in one XCD's L2.
__global__ __launch_bounds__(512, 4) void conv_mfma(
    const float* __restrict__ x, const float* __restrict__ w,
    const float* __restrict__ bias, float* __restrict__ out)
{
    __shared__ __align__(16) ushort_t Wl[O_ * LDB];   // 56,832 B (only LDS)

    // xcd = bid&7; groups with g%8==c all on xcd c.
    const int bid = blockIdx.x;
    const int c   = bid & 7;
    const int s   = bid >> 3;            // 0..135
    const int g   = c + ((s >> 3) << 3);
    if (g >= G_) return;                 // uniform; before the barrier
    const int mt  = s & 7;
    const int m0  = mt * 256;

    const int tid  = threadIdx.x;
    const int wave = tid >> 6;
    const int lane = tid & 63;
    const int ln   = lane & 15;
    const int q    = lane >> 4;

    const int m0r = m0 + wave * 32;      // this wave's 32 rows
    const int b   = m0r >> 9;
    const int tb  = m0r & 511;

    // Direct-A pointers + zero-masks, per (s2,kk): row t = tb+s2*16+ln+kk-1.
    const float* pA[2][3];
    unsigned msk[2][3];
    #pragma unroll
    for (int s2 = 0; s2 < 2; ++s2)
        #pragma unroll
        for (int kk = 0; kk < 3; ++kk) {
            int t = tb + s2 * 16 + ln + kk - 1;
            msk[s2][kk] = ((unsigned)t < (unsigned)T_) ? 0xFFFFFFFFu : 0u;
            int tc = t < 0 ? 0 : (t > T_ - 1 ? T_ - 1 : t);
            pA[s2][kk] = x + ((size_t)((b * T_ + tc) * G_ + g) * F_ + q * 8);
        }

    floatx4 u[2][3][2];                  // 12 dwordx4 in flight per fb
    auto issueA = [&](int fb) {
        #pragma unroll
        for (int s2 = 0; s2 < 2; ++s2)
            #pragma unroll
            for (int kk = 0; kk < 3; ++kk) {
                u[s2][kk][0] = *(const floatx4*)(pA[s2][kk] + fb * 32);
                u[s2][kk][1] = *(const floatx4*)(pA[s2][kk] + fb * 32 + 4);
            }
    };

    issueA(0);   // in flight under the whole weight stage + barrier

    // Fused weight stage: 12 consecutive f32 of w[g][o] per task (16B-aligned);
    // floats j=0..11 are (f,kk)=(4u+j/3, j%3); three uint2 -> Wl[o*LDB+kk*96+4u].
    {
        const float* wg = w + (size_t)g * (O_ * KD);
        #pragma unroll
        for (int i = 0; i < 5; ++i) {
            int task = i * 512 + tid;
            if (task < 2304) {
                int o = task / 24;
                int uu = task - o * 24;
                const float* p = wg + o * KD + uu * 12;
                float4 A = *(const float4*)(p);
                float4 B = *(const float4*)(p + 4);
                float4 C = *(const float4*)(p + 8);
                int base = o * LDB + uu * 4;
                uint2 d0, d1, d2;
                d0.x = pk2(A.x, A.w);  d0.y = pk2(B.z, C.y);   // kk=0
                d1.x = pk2(A.y, B.x);  d1.y = pk2(B.w, C.z);   // kk=1
                d2.x = pk2(A.z, B.y);  d2.y = pk2(C.x, C.w);   // kk=2
                *(uint2*)&Wl[base]       = d0;
                *(uint2*)&Wl[base +  96] = d1;
                *(uint2*)&Wl[base + 192] = d2;
            }
        }
    }

    float bv[6];
    #pragma unroll
    for (int nt = 0; nt < 6; ++nt) bv[nt] = bias[g * O_ + nt * 16 + ln];

    __syncthreads();   // the only barrier

    floatx4 acc[2][6];
    #pragma unroll
    for (int s2 = 0; s2 < 2; ++s2)
        #pragma unroll
        for (int nt = 0; nt < 6; ++nt)
            acc[s2][nt] = (floatx4){0.f, 0.f, 0.f, 0.f};

    short8 a[2][3];
    auto packA = [&]() {   // consumes u (vmcnt wait), applies boundary zero-mask
        #pragma unroll
        for (int s2 = 0; s2 < 2; ++s2)
            #pragma unroll
            for (int kk = 0; kk < 3; ++kk) {
                unsigned mk = msk[s2][kk];
                uintx4 d;
                d[0] = cvtpk(u[s2][kk][0][0], u[s2][kk][0][1]) & mk;
                d[1] = cvtpk(u[s2][kk][0][2], u[s2][kk][0][3]) & mk;
                d[2] = cvtpk(u[s2][kk][1][0], u[s2][kk][1][1]) & mk;
                d[3] = cvtpk(u[s2][kk][1][2], u[s2][kk][1][3]) & mk;
                a[s2][kk] = __builtin_bit_cast(short8, d);
            }
    };

    #pragma unroll
    for (int fb = 0; fb < 3; ++fb) {
        packA();                      // waits on this fb's 12 loads
        if (fb < 2) issueA(fb + 1);   // next burst hides under 36 MFMAs
        #pragma unroll
        for (int kk = 0; kk < 3; ++kk) {
            const int c32 = (kk * 3 + fb) * 32;   // Wl column kd = kk*96 + fb*32
            #pragma unroll
            for (int nt = 0; nt < 6; ++nt) {
                const short8 bbv = *(const short8*)&Wl[(nt * 16 + ln) * LDB + c32 + q * 8];
                acc[0][nt] = __builtin_amdgcn_mfma_f32_16x16x32_bf16(a[0][kk], bbv, acc[0][nt], 0, 0, 0);
                acc[1][nt] = __builtin_amdgcn_mfma_f32_16x16x32_bf16(a[1][kk], bbv, acc[1][nt], 0, 0, 0);
            }
        }
    }

    // Epilogue: D row = q*4 + reg, col = ln; + bias; f32 out (full 384-B rows
    // per block -> clean full-line writes, round-2 measured behavior).
    #pragma unroll
    for (int s2 = 0; s2 < 2; ++s2) {
        int mbase = m0 + wave * 32 + s2 * 16 + q * 4;
        #pragma unroll
        for (int nt = 0; nt < 6; ++nt) {
            int o = nt * 16 + ln;
            #pragma unroll
            for (int r = 0; r < 4; ++r) {
                int m = mbase + r;
                out[(size_t)(m * G_ + g) * O_ + o] = acc[s2][nt][r] + bv[nt];
            }
        }
    }
}

extern "C" void kernel_launch(void* const* d_in, const int* in_sizes, int n_in,
                              void* d_out, int out_size, void* d_ws, size_t ws_size,
                              hipStream_t stream) {
    const float* x    = (const float*)d_in[0];
    const float* w    = (const float*)d_in[1];
    const float* bias = (const float*)d_in[2];
    float* out = (float*)d_out;
    conv_mfma<<<dim3(1088), dim3(512), 0, stream>>>(x, w, bias, out);
}